// Round 4
// baseline (276.172 us; speedup 1.0000x reference)
//
#include <hip/hip_runtime.h>
#include <cstddef>
#include <cstdint>

#define T_SEQ 100

typedef __attribute__((ext_vector_type(8))) short bfrag;
typedef __attribute__((ext_vector_type(4))) float f4;

union FragU { uint32_t u[4]; bfrag v; };

__device__ __forceinline__ float fast_tanh(float x) {
    float e = __expf(2.0f * x);
    float r = __builtin_amdgcn_rcpf(e + 1.0f);
    return 1.0f - 2.0f * r;
}

__device__ __forceinline__ float exp2_fast(float x) {
#if __has_builtin(__builtin_amdgcn_exp2f)
    return __builtin_amdgcn_exp2f(x);
#else
    return __expf(x * 0.6931471805599453f);
#endif
}

// tanh(o)*scale = scale - 2*scale / (2^(o*2*log2e) + 1)
__device__ __forceinline__ float tanh_mul(float o, float scale, float s2) {
    float rr = __builtin_amdgcn_rcpf(exp2_fast(o * 2.8853900817779268f) + 1.0f);
    return fmaf(-s2, rr, scale);
}

// f32 pair -> packed bf16 (RNE), one instruction per pair (register-only asm).
#if __has_builtin(__builtin_amdgcn_cvt_pk_bf16_f32)
typedef __attribute__((ext_vector_type(2))) __bf16 bf16x2;
__device__ __forceinline__ uint32_t cvtpk(float lo, float hi) {
    bf16x2 p = __builtin_amdgcn_cvt_pk_bf16_f32(lo, hi);
    return __builtin_bit_cast(uint32_t, p);
}
#else
__device__ __forceinline__ uint32_t cvtpk(float lo, float hi) {
    uint32_t r;
    asm("v_cvt_pk_bf16_f32 %0, %1, %2" : "=v"(r) : "v"(lo), "v"(hi));
    return r;
}
#endif

__device__ __forceinline__ void pack8(const float a[8], bfrag& out) {
    FragU O;
    #pragma unroll
    for (int q = 0; q < 4; ++q)
        O.u[q] = cvtpk(a[2 * q], a[2 * q + 1]);
    out = O.v;
}

__device__ __forceinline__ f4 mfma_(bfrag a, bfrag b, f4 c) {
    return __builtin_amdgcn_mfma_f32_16x16x32_bf16(a, b, c, 0, 0, 0);
}

// 16B global->LDS async copy in the VERIFIED configuration (m97/m201):
// size=16, offset=0, true addrspacecast pointers (no integer truncation,
// no reliance on inst_offset semantics). Lane lambda's 16B from its own
// per-lane global address land at lds_base + lambda*16 (wave-uniform base).
// Fire-and-forget: holds no VGPRs, cannot be sunk by the scheduler.
__device__ __forceinline__ void gl_lds16(const float* gp, float* lp) {
#if __has_builtin(__builtin_amdgcn_global_load_lds)
    __builtin_amdgcn_global_load_lds(
        (const __attribute__((address_space(1))) void*)gp,
        (__attribute__((address_space(3))) void*)lp,
        16, 0, 0);
#else
    #pragma unroll
    for (int j = 0; j < 4; ++j) lp[4 * threadIdx.x + j] = gp[j];
#endif
}

// ============================================================================
// Serial recurrence: one wave = 16 elements, Euler step (1 feval/t).
// x(t) staged through an 8-slot LDS ring via global_load_lds (2 x 16B per
// time-step), prefetch distance 7 bodies, consumed after a COUNTED
// s_waitcnt vmcnt(12) — never drained to 0 in the loop. Safety (in-order
// vmcnt retirement, 2 loads + 2 stores per body, 14-load prefill): at every
// iteration the ops issued after the needed 2-load group number >= 12, so
// vmcnt(12) guarantees the group landed while keeping ~6 bodies (~1500 cy)
// of loads in flight. Scales precomputed into LDS once.
// z(t) stored packed-bf16 to zws; mu computed by the parallel mu_kernel.
// ============================================================================
__global__ __launch_bounds__(64, 1)
void latode_serial(const float* __restrict__ dt,  const float* __restrict__ x,
                   const float* __restrict__ We1, const float* __restrict__ be1,
                   const float* __restrict__ We2, const float* __restrict__ be2,
                   const float* __restrict__ Wf1, const float* __restrict__ bf1,
                   const float* __restrict__ Wf2, const float* __restrict__ bf2,
                   uint32_t* __restrict__ zws, int B)
{
    const int l = threadIdx.x;
    const int g = l >> 4;
    const int m = l & 15;
    const int e = blockIdx.x * 16 + m;
    const int js0 = 8 * (m >> 2) + (m & 3);
    const int js1 = js0 + 4;

    __shared__ __align__(16) float slds[T_SEQ * 16];  // scale[t][e_local], 6.4 KB
    __shared__ __align__(16) float ring[8 * 512];     // 8 slots x 2048 B

    float tmp[8];
    bfrag A0, A1, X0, X1, W0, W1;

    #pragma unroll
    for (int jj = 0; jj < 8; ++jj) {
        int sig = 16 * (jj >> 2) + 4 * g + (jj & 3);
        tmp[jj] = (js0 < 20) ? Wf1[sig * 20 + js0] : 0.0f;
    }
    pack8(tmp, A0);
    #pragma unroll
    for (int jj = 0; jj < 8; ++jj) {
        int sig = 16 * (jj >> 2) + 4 * g + (jj & 3);
        tmp[jj] = (js1 < 20) ? Wf1[sig * 20 + js1] : 0.0f;
    }
    pack8(tmp, A1);
    #pragma unroll
    for (int jj = 0; jj < 8; ++jj) {
        int kx = 8 * g + jj;
        tmp[jj] = (js0 < 20) ? Wf1[(32 + kx) * 20 + js0] : 0.0f;
    }
    pack8(tmp, X0);
    #pragma unroll
    for (int jj = 0; jj < 8; ++jj) {
        int kx = 8 * g + jj;
        tmp[jj] = (js1 < 20) ? Wf1[(32 + kx) * 20 + js1] : 0.0f;
    }
    pack8(tmp, X1);
    #pragma unroll
    for (int jj = 0; jj < 8; ++jj) {
        int j = 8 * g + jj;
        tmp[jj] = (j < 20) ? Wf2[j * 32 + m] : 0.0f;
    }
    pack8(tmp, W0);
    #pragma unroll
    for (int jj = 0; jj < 8; ++jj) {
        int j = 8 * g + jj;
        tmp[jj] = (j < 20) ? Wf2[j * 32 + 16 + m] : 0.0f;
    }
    pack8(tmp, W1);

    f4 bias0, bias1, cb0, cb1;
    #pragma unroll
    for (int r = 0; r < 4; ++r) {
        bias0[r] = bf2[4 * g + r];
        bias1[r] = bf2[16 + 4 * g + r];
        int j0 = 8 * g + r;     cb0[r] = (j0 < 20) ? bf1[j0] : 0.0f;
        int j1 = 8 * g + r + 4; cb1[r] = (j1 < 20) ? bf1[j1] : 0.0f;
    }

    const float* xe = x + (size_t)e * T_SEQ * 32;
    uint32_t* zrow = zws + (size_t)e * T_SEQ * 16;

    // ---- stage scales into LDS (one-time; compiler-managed waits) ----
    {
        const float* dtb = dt + (size_t)blockIdx.x * 16 * T_SEQ * 2;  // 3200 f
        #pragma unroll 1
        for (int i = l; i < 800; i += 64) {
            float4 v = *(const float4*)(dtb + 4 * i);
            int p0 = 2 * i;            // pair index (even; 100 even => t0 even)
            int el = p0 / 100;         // element 0..15
            int t0 = p0 - el * 100;    // even, <= 98
            slds[t0 * 16 + el]       = (v.y - v.x) * 0.01f;
            slds[(t0 + 1) * 16 + el] = (v.w - v.z) * 0.01f;
        }
    }

    // ---- z0 encode (scalar fp32, once) — BEFORE the ring prefill so the
    //      compiler's waits for these plain loads can't drain the prefetch ----
    float z[8];
    {
        float x0v[32];
        #pragma unroll
        for (int i = 0; i < 32; i += 4) {
            float4 v = *(const float4*)(xe + i);
            x0v[i] = v.x; x0v[i+1] = v.y; x0v[i+2] = v.z; x0v[i+3] = v.w;
        }
        float h10[10];
        #pragma unroll
        for (int r = 0; r < 10; ++r) {
            float s = be1[r];
            #pragma unroll
            for (int i = 0; i < 32; ++i) s += x0v[i] * We1[i * 10 + r];
            h10[r] = fast_tanh(s);
        }
        #pragma unroll
        for (int jj = 0; jj < 8; ++jj) {
            int sig = 16 * (jj >> 2) + 4 * g + (jj & 3);
            float s = be2[sig];
            #pragma unroll
            for (int r = 0; r < 10; ++r) s += h10[r] * We2[r * 32 + sig];
            z[jj] = fast_tanh(s);
        }
    }

    // ---- ring prefill: times 0..6 into slots 0..6 (14 loads in flight) ----
    const float* xg = xe + 8 * g;        // lane's global base (its 8 floats)
    auto issue2 = [&](int tf, int slot) {
        const float* gp = xg + (size_t)tf * 32;
        float* lp = ring + slot * 512;
        gl_lds16(gp,     lp);            // lane's floats 0..3 -> lp + 4*l
        gl_lds16(gp + 4, lp + 256);      // lane's floats 4..7 -> lp+256 + 4*l
    };
    #pragma unroll
    for (int tau = 0; tau < 7; ++tau) issue2(tau, tau);

    // consume: 2x ds_read_b128 from ring (16B/lane stride — conflict-free),
    // pack, cx MFMAs, scale from LDS.
    f4 cx0, cx1;
    float scale;
    auto consume = [&](int tc, f4& o0, f4& o1, float& os) {
        const float* rs = ring + (size_t)(tc & 7) * 512;
        float4 a = *(const float4*)(rs + 4 * l);
        float4 b = *(const float4*)(rs + 256 + 4 * l);
        float xt[8] = { a.x, a.y, a.z, a.w, b.x, b.y, b.z, b.w };
        bfrag xf; pack8(xt, xf);
        o0 = mfma_(X0, xf, cb0);
        o1 = mfma_(X1, xf, cb1);
        int ts = (tc > T_SEQ - 1) ? (T_SEQ - 1) : tc;
        os = slds[ts * 16 + m];
    };

    asm volatile("s_waitcnt vmcnt(12)" ::: "memory");
    __builtin_amdgcn_sched_barrier(0);
    consume(0, cx0, cx1, scale);

    #pragma unroll 1
    for (int t = 0; t < T_SEQ; ++t) {
        // prefetch time t+7 (clamped content, constant op count, rotating slot)
        int tf = t + 7; if (tf > T_SEQ - 1) tf = T_SEQ - 1;
        issue2(tf, (t + 7) & 7);

        asm volatile("s_waitcnt vmcnt(12)" ::: "memory");
        __builtin_amdgcn_sched_barrier(0);

        f4 ncx0, ncx1; float nsc;
        consume(t + 1, ncx0, ncx1, nsc);   // data landed ~6 bodies ago

        // ---- Euler body for time t ----
        const float s2 = scale + scale;
        bfrag bb; pack8(z, bb);
        f4 p0 = mfma_(A0, bb, cx0);
        f4 p1 = mfma_(A1, bb, cx1);
        float pr[8];
        #pragma unroll
        for (int r = 0; r < 4; ++r) {
            pr[r]     = fmaxf(p0[r], 0.0f);
            pr[4 + r] = fmaxf(p1[r], 0.0f);
        }
        bfrag pf; pack8(pr, pf);
        f4 o0 = mfma_(W0, pf, bias0);
        f4 o1 = mfma_(W1, pf, bias1);
        #pragma unroll
        for (int r = 0; r < 4; ++r) {
            z[r]     += tanh_mul(o0[r], scale, s2);
            z[4 + r] += tanh_mul(o1[r], scale, s2);
        }
        bfrag zf; pack8(z, zf);
        FragU P; P.v = zf;
        uint32_t* rowp = zrow + (uint32_t)t * 16;
        *(uint2*)(rowp + 2 * g)     = make_uint2(P.u[0], P.u[1]);
        *(uint2*)(rowp + 8 + 2 * g) = make_uint2(P.u[2], P.u[3]);

        cx0 = ncx0; cx1 = ncx1; scale = nsc;
    }
}

// Parallel mu head: one thread per (e,t) row.
__global__ __launch_bounds__(256, 4)
void mu_kernel(const uint32_t* __restrict__ zws,
               const float* __restrict__ Wm1, const float* __restrict__ bm1,
               const float* __restrict__ Wm2, const float* __restrict__ bm2,
               float* __restrict__ out, int nrows)
{
    int row = blockIdx.x * 256 + threadIdx.x;
    if (row >= nrows) return;
    const uint4* zp = (const uint4*)(zws + (size_t)row * 16);
    uint4 q0 = zp[0], q1 = zp[1], q2 = zp[2], q3 = zp[3];
    uint32_t du[16] = { q0.x, q0.y, q0.z, q0.w, q1.x, q1.y, q1.z, q1.w,
                        q2.x, q2.y, q2.z, q2.w, q3.x, q3.y, q3.z, q3.w };
    float zf[32];
    #pragma unroll
    for (int d = 0; d < 16; ++d) {
        uint32_t u = du[d];
        zf[2 * d]     = __uint_as_float(u << 16);
        zf[2 * d + 1] = __uint_as_float(u & 0xFFFF0000u);
    }
    float v[10];
    #pragma unroll
    for (int r = 0; r < 10; ++r) v[r] = bm1[r];
    #pragma unroll
    for (int i = 0; i < 32; ++i) {
        float zi = zf[i];
        #pragma unroll
        for (int r = 0; r < 10; ++r) v[r] = fmaf(zi, Wm1[i * 10 + r], v[r]);
    }
    float mu = bm2[0];
    #pragma unroll
    for (int r = 0; r < 10; ++r) mu += fast_tanh(v[r]) * Wm2[r];
    out[row] = mu;
}

// ============================================================================
// Fallback (ws too small / B not /16): fused Euler, mu in-loop.
// ============================================================================
__global__ __launch_bounds__(64, 1)
void latode_fused(const float* __restrict__ dt,  const float* __restrict__ x,
                  const float* __restrict__ We1, const float* __restrict__ be1,
                  const float* __restrict__ We2, const float* __restrict__ be2,
                  const float* __restrict__ Wf1, const float* __restrict__ bf1,
                  const float* __restrict__ Wf2, const float* __restrict__ bf2,
                  const float* __restrict__ Wm1, const float* __restrict__ bm1,
                  const float* __restrict__ Wm2, const float* __restrict__ bm2,
                  float* __restrict__ out, int B)
{
    const int l = threadIdx.x;
    const int g = l >> 4;
    const int m = l & 15;
    const int e = blockIdx.x * 16 + m;
    if (e >= B) return;
    const int js0 = 8 * (m >> 2) + (m & 3);
    const int js1 = js0 + 4;

    float tmp[8];
    bfrag A0, A1, X0, X1, W0, W1, M0;
    #pragma unroll
    for (int jj = 0; jj < 8; ++jj) {
        int sig = 16 * (jj >> 2) + 4 * g + (jj & 3);
        tmp[jj] = (js0 < 20) ? Wf1[sig * 20 + js0] : 0.0f;
    }
    pack8(tmp, A0);
    #pragma unroll
    for (int jj = 0; jj < 8; ++jj) {
        int sig = 16 * (jj >> 2) + 4 * g + (jj & 3);
        tmp[jj] = (js1 < 20) ? Wf1[sig * 20 + js1] : 0.0f;
    }
    pack8(tmp, A1);
    #pragma unroll
    for (int jj = 0; jj < 8; ++jj) {
        int kx = 8 * g + jj;
        tmp[jj] = (js0 < 20) ? Wf1[(32 + kx) * 20 + js0] : 0.0f;
    }
    pack8(tmp, X0);
    #pragma unroll
    for (int jj = 0; jj < 8; ++jj) {
        int kx = 8 * g + jj;
        tmp[jj] = (js1 < 20) ? Wf1[(32 + kx) * 20 + js1] : 0.0f;
    }
    pack8(tmp, X1);
    #pragma unroll
    for (int jj = 0; jj < 8; ++jj) {
        int j = 8 * g + jj;
        tmp[jj] = (j < 20) ? Wf2[j * 32 + m] : 0.0f;
    }
    pack8(tmp, W0);
    #pragma unroll
    for (int jj = 0; jj < 8; ++jj) {
        int j = 8 * g + jj;
        tmp[jj] = (j < 20) ? Wf2[j * 32 + 16 + m] : 0.0f;
    }
    pack8(tmp, W1);
    #pragma unroll
    for (int jj = 0; jj < 8; ++jj) {
        int sig = 16 * (jj >> 2) + 4 * g + (jj & 3);
        tmp[jj] = (m < 10) ? Wm1[sig * 10 + m] : 0.0f;
    }
    pack8(tmp, M0);

    f4 bias0, bias1, cb0, cb1, bmv;
    float wm2r[4];
    #pragma unroll
    for (int r = 0; r < 4; ++r) {
        bias0[r] = bf2[4 * g + r];
        bias1[r] = bf2[16 + 4 * g + r];
        int j0 = 8 * g + r;     cb0[r] = (j0 < 20) ? bf1[j0] : 0.0f;
        int j1 = 8 * g + r + 4; cb1[r] = (j1 < 20) ? bf1[j1] : 0.0f;
        int vr = 4 * g + r;
        bmv[r]  = (vr < 10) ? bm1[vr] : 0.0f;
        wm2r[r] = (vr < 10) ? Wm2[vr] : 0.0f;
    }

    const float* xe  = x  + (size_t)e * T_SEQ * 32;
    const float* dte = dt + (size_t)e * T_SEQ * 2;

    float z[8];
    {
        float x0v[32];
        #pragma unroll
        for (int i = 0; i < 32; i += 4) {
            float4 v = *(const float4*)(xe + i);
            x0v[i] = v.x; x0v[i+1] = v.y; x0v[i+2] = v.z; x0v[i+3] = v.w;
        }
        float h10[10];
        #pragma unroll
        for (int r = 0; r < 10; ++r) {
            float s = be1[r];
            #pragma unroll
            for (int i = 0; i < 32; ++i) s += x0v[i] * We1[i * 10 + r];
            h10[r] = fast_tanh(s);
        }
        #pragma unroll
        for (int jj = 0; jj < 8; ++jj) {
            int sig = 16 * (jj >> 2) + 4 * g + (jj & 3);
            float s = be2[sig];
            #pragma unroll
            for (int r = 0; r < 10; ++r) s += h10[r] * We2[r * 32 + sig];
            z[jj] = fast_tanh(s);
        }
    }

    const float bm2s = bm2[0];
    f4 cx0, cx1;
    float scale;
    {
        float4 va = *(const float4*)(xe + 8 * g);
        float4 vb = *(const float4*)(xe + 8 * g + 4);
        float2 dd = *(const float2*)(dte);
        float xt[8] = { va.x, va.y, va.z, va.w, vb.x, vb.y, vb.z, vb.w };
        bfrag xf; pack8(xt, xf);
        cx0 = mfma_(X0, xf, cb0);
        cx1 = mfma_(X1, xf, cb1);
        scale = (dd.y - dd.x) * 0.01f;
    }

    for (int t = 0; t < T_SEQ; ++t) {
        int tn = (t + 1 < T_SEQ) ? (t + 1) : t;
        const float* xr = xe + tn * 32 + 8 * g;
        float4 na = *(const float4*)(xr);
        float4 nb = *(const float4*)(xr + 4);
        float2 nd = *(const float2*)(dte + 2 * tn);
        const float s2 = scale + scale;

        bfrag bb; pack8(z, bb);
        f4 p0 = mfma_(A0, bb, cx0);
        f4 p1 = mfma_(A1, bb, cx1);
        float pr[8];
        #pragma unroll
        for (int r = 0; r < 4; ++r) {
            pr[r]     = fmaxf(p0[r], 0.0f);
            pr[4 + r] = fmaxf(p1[r], 0.0f);
        }
        bfrag pf; pack8(pr, pf);
        f4 o0 = mfma_(W0, pf, bias0);
        f4 o1 = mfma_(W1, pf, bias1);
        #pragma unroll
        for (int r = 0; r < 4; ++r) {
            z[r]     += tanh_mul(o0[r], scale, s2);
            z[4 + r] += tanh_mul(o1[r], scale, s2);
        }

        {
            float xt[8] = { na.x, na.y, na.z, na.w, nb.x, nb.y, nb.z, nb.w };
            bfrag xf; pack8(xt, xf);
            cx0 = mfma_(X0, xf, cb0);
            cx1 = mfma_(X1, xf, cb1);
            scale = (nd.y - nd.x) * 0.01f;
        }

        bfrag zf; pack8(z, zf);
        f4 vv = mfma_(M0, zf, bmv);
        float p = 0.0f;
        #pragma unroll
        for (int r = 0; r < 4; ++r) p += fast_tanh(vv[r]) * wm2r[r];
        p += __shfl_xor(p, 16, 64);
        p += __shfl_xor(p, 32, 64);
        if (l < 16) out[(size_t)e * T_SEQ + t] = p + bm2s;
    }
}

extern "C" void kernel_launch(void* const* d_in, const int* in_sizes, int n_in,
                              void* d_out, int out_size, void* d_ws, size_t ws_size,
                              hipStream_t stream) {
    const float* dt  = (const float*)d_in[0];
    const float* x   = (const float*)d_in[1];
    const float* We1 = (const float*)d_in[2];
    const float* be1 = (const float*)d_in[3];
    const float* We2 = (const float*)d_in[4];
    const float* be2 = (const float*)d_in[5];
    const float* Wf1 = (const float*)d_in[6];
    const float* bf1 = (const float*)d_in[7];
    const float* Wf2 = (const float*)d_in[8];
    const float* bf2 = (const float*)d_in[9];
    const float* Wm1 = (const float*)d_in[10];
    const float* bm1 = (const float*)d_in[11];
    const float* Wm2 = (const float*)d_in[12];
    const float* bm2 = (const float*)d_in[13];
    float* out = (float*)d_out;

    const int B = in_sizes[0] / (T_SEQ * 2);   // 8192
    const size_t zbytes = (size_t)B * T_SEQ * 32 * 2;

    if (ws_size >= zbytes && (B % 16) == 0) {
        hipLaunchKernelGGL(latode_serial, dim3(B / 16), dim3(64), 0, stream,
                           dt, x, We1, be1, We2, be2, Wf1, bf1, Wf2, bf2,
                           (uint32_t*)d_ws, B);
        int nrows = B * T_SEQ;
        hipLaunchKernelGGL(mu_kernel, dim3((nrows + 255) / 256), dim3(256), 0, stream,
                           (const uint32_t*)d_ws, Wm1, bm1, Wm2, bm2, out, nrows);
    } else {
        hipLaunchKernelGGL(latode_fused, dim3((B + 15) / 16), dim3(64), 0, stream,
                           dt, x, We1, be1, We2, be2, Wf1, bf1, Wf2, bf2,
                           Wm1, bm1, Wm2, bm2, out, B);
    }
}

// Round 5
// 223.247 us; speedup vs baseline: 1.2371x; 1.2371x over previous
//
#include <hip/hip_runtime.h>
#include <cstddef>
#include <cstdint>

#define T_SEQ 100

typedef __attribute__((ext_vector_type(8))) short bfrag;
typedef __attribute__((ext_vector_type(4))) float f4;

union FragU { uint32_t u[4]; bfrag v; };

__device__ __forceinline__ float fast_tanh(float x) {
    float e = __expf(2.0f * x);
    float r = __builtin_amdgcn_rcpf(e + 1.0f);
    return 1.0f - 2.0f * r;
}

__device__ __forceinline__ float exp2_fast(float x) {
#if __has_builtin(__builtin_amdgcn_exp2f)
    return __builtin_amdgcn_exp2f(x);
#else
    return __expf(x * 0.6931471805599453f);
#endif
}

// tanh(o)*scale = scale - 2*scale / (2^(o*2*log2e) + 1)
__device__ __forceinline__ float tanh_mul(float o, float scale, float s2) {
    float rr = __builtin_amdgcn_rcpf(exp2_fast(o * 2.8853900817779268f) + 1.0f);
    return fmaf(-s2, rr, scale);
}

// f32 pair -> packed bf16 (RNE), one instruction per pair (register-only asm).
#if __has_builtin(__builtin_amdgcn_cvt_pk_bf16_f32)
typedef __attribute__((ext_vector_type(2))) __bf16 bf16x2;
__device__ __forceinline__ uint32_t cvtpk(float lo, float hi) {
    bf16x2 p = __builtin_amdgcn_cvt_pk_bf16_f32(lo, hi);
    return __builtin_bit_cast(uint32_t, p);
}
#else
__device__ __forceinline__ uint32_t cvtpk(float lo, float hi) {
    uint32_t r;
    asm("v_cvt_pk_bf16_f32 %0, %1, %2" : "=v"(r) : "v"(lo), "v"(hi));
    return r;
}
#endif

__device__ __forceinline__ void pack8(const float a[8], bfrag& out) {
    FragU O;
    #pragma unroll
    for (int q = 0; q < 4; ++q)
        O.u[q] = cvtpk(a[2 * q], a[2 * q + 1]);
    out = O.v;
}

__device__ __forceinline__ f4 mfma_(bfrag a, bfrag b, f4 c) {
    return __builtin_amdgcn_mfma_f32_16x16x32_bf16(a, b, c, 0, 0, 0);
}

// 16B global->LDS async copy, verified configuration (size=16, offset=0,
// true addrspacecast pointers). Lane lambda's 16B land at lds_base+lambda*16.
__device__ __forceinline__ void gl_lds16(const float* gp, float* lp) {
#if __has_builtin(__builtin_amdgcn_global_load_lds)
    __builtin_amdgcn_global_load_lds(
        (const __attribute__((address_space(1))) void*)gp,
        (__attribute__((address_space(3))) void*)lp,
        16, 0, 0);
#else
    #pragma unroll
    for (int j = 0; j < 4; ++j) lp[4 * threadIdx.x + j] = gp[j];
#endif
}

typedef __attribute__((address_space(3))) const float* lds_cfp;

// ============================================================================
// Serial recurrence: one wave = 16 elements, Euler step (1 feval/t).
// x(t) staged through an 8-slot LDS ring via global_load_lds (2 x 16B per
// time-step), prefetch distance 7, consumed after a COUNTED
// s_waitcnt vmcnt(12) (clobber-free asm, matching the verified m201 wait
// pattern). The consume's LDS reads are a single REGISTER-ONLY volatile asm
// block (2x ds_read_b128 + ds_read_b32 + embedded s_waitcnt lgkmcnt(0)):
// no memory operands -> the waitcnt pass cannot insert a protective
// vmcnt(0) drain before them (the r4 slowdown), and the embedded lgkmcnt
// makes the outputs complete when the block retires (regalloc-safe).
// Count safety (in-order vmcnt retire): the 12 loads of the 6 younger
// iterations always sit between the needed 2-load group and the wait
// (volatile-ordered), so vmcnt(12) retires the group; stores only add
// older/newer ops that retire harmlessly earlier.
// z(t) stored packed-bf16 to zws; mu computed by the parallel mu_kernel.
// ============================================================================
__global__ __launch_bounds__(64, 1)
void latode_serial(const float* __restrict__ dt,  const float* __restrict__ x,
                   const float* __restrict__ We1, const float* __restrict__ be1,
                   const float* __restrict__ We2, const float* __restrict__ be2,
                   const float* __restrict__ Wf1, const float* __restrict__ bf1,
                   const float* __restrict__ Wf2, const float* __restrict__ bf2,
                   uint32_t* __restrict__ zws, int B)
{
    const int l = threadIdx.x;
    const int g = l >> 4;
    const int m = l & 15;
    const int e = blockIdx.x * 16 + m;
    const int js0 = 8 * (m >> 2) + (m & 3);
    const int js1 = js0 + 4;

    __shared__ __align__(16) float slds[T_SEQ * 16];  // scale[t][e_local]
    __shared__ __align__(16) float ring[8 * 512];     // 8 slots x 2048 B

    float tmp[8];
    bfrag A0, A1, X0, X1, W0, W1;

    #pragma unroll
    for (int jj = 0; jj < 8; ++jj) {
        int sig = 16 * (jj >> 2) + 4 * g + (jj & 3);
        tmp[jj] = (js0 < 20) ? Wf1[sig * 20 + js0] : 0.0f;
    }
    pack8(tmp, A0);
    #pragma unroll
    for (int jj = 0; jj < 8; ++jj) {
        int sig = 16 * (jj >> 2) + 4 * g + (jj & 3);
        tmp[jj] = (js1 < 20) ? Wf1[sig * 20 + js1] : 0.0f;
    }
    pack8(tmp, A1);
    #pragma unroll
    for (int jj = 0; jj < 8; ++jj) {
        int kx = 8 * g + jj;
        tmp[jj] = (js0 < 20) ? Wf1[(32 + kx) * 20 + js0] : 0.0f;
    }
    pack8(tmp, X0);
    #pragma unroll
    for (int jj = 0; jj < 8; ++jj) {
        int kx = 8 * g + jj;
        tmp[jj] = (js1 < 20) ? Wf1[(32 + kx) * 20 + js1] : 0.0f;
    }
    pack8(tmp, X1);
    #pragma unroll
    for (int jj = 0; jj < 8; ++jj) {
        int j = 8 * g + jj;
        tmp[jj] = (j < 20) ? Wf2[j * 32 + m] : 0.0f;
    }
    pack8(tmp, W0);
    #pragma unroll
    for (int jj = 0; jj < 8; ++jj) {
        int j = 8 * g + jj;
        tmp[jj] = (j < 20) ? Wf2[j * 32 + 16 + m] : 0.0f;
    }
    pack8(tmp, W1);

    f4 bias0, bias1, cb0, cb1;
    #pragma unroll
    for (int r = 0; r < 4; ++r) {
        bias0[r] = bf2[4 * g + r];
        bias1[r] = bf2[16 + 4 * g + r];
        int j0 = 8 * g + r;     cb0[r] = (j0 < 20) ? bf1[j0] : 0.0f;
        int j1 = 8 * g + r + 4; cb1[r] = (j1 < 20) ? bf1[j1] : 0.0f;
    }

    const float* xe = x + (size_t)e * T_SEQ * 32;
    uint32_t* zrow = zws + (size_t)e * T_SEQ * 16;

    // ---- stage scales into LDS (one-time, plain ops, before any DMA) ----
    {
        const float* dtb = dt + (size_t)blockIdx.x * 16 * T_SEQ * 2;  // 3200 f
        #pragma unroll 1
        for (int i = l; i < 800; i += 64) {
            float4 v = *(const float4*)(dtb + 4 * i);
            int p0 = 2 * i;            // even pair index
            int el = p0 / 100;         // element 0..15
            int t0 = p0 - el * 100;    // even, <= 98
            slds[t0 * 16 + el]       = (v.y - v.x) * 0.01f;
            slds[(t0 + 1) * 16 + el] = (v.w - v.z) * 0.01f;
        }
    }

    // ---- z0 encode (scalar fp32, once; before the ring prefill) ----
    float z[8];
    {
        float x0v[32];
        #pragma unroll
        for (int i = 0; i < 32; i += 4) {
            float4 v = *(const float4*)(xe + i);
            x0v[i] = v.x; x0v[i+1] = v.y; x0v[i+2] = v.z; x0v[i+3] = v.w;
        }
        float h10[10];
        #pragma unroll
        for (int r = 0; r < 10; ++r) {
            float s = be1[r];
            #pragma unroll
            for (int i = 0; i < 32; ++i) s += x0v[i] * We1[i * 10 + r];
            h10[r] = fast_tanh(s);
        }
        #pragma unroll
        for (int jj = 0; jj < 8; ++jj) {
            int sig = 16 * (jj >> 2) + 4 * g + (jj & 3);
            float s = be2[sig];
            #pragma unroll
            for (int r = 0; r < 10; ++r) s += h10[r] * We2[r * 32 + sig];
            z[jj] = fast_tanh(s);
        }
    }

    // ---- ring prefill: times 0..6 into slots 0..6 (14 loads in flight) ----
    const float* xg = xe + 8 * g;        // lane's global base (its 8 floats)
    auto issue2 = [&](int tf, int slot) {
        const float* gp = xg + (size_t)tf * 32;
        float* lp = ring + slot * 512;
        gl_lds16(gp,     lp);            // lane's floats 0..3 -> lp + 4*l
        gl_lds16(gp + 4, lp + 256);      // lane's floats 4..7 -> lp+256 + 4*l
    };
    #pragma unroll
    for (int tau = 0; tau < 7; ++tau) issue2(tau, tau);

    // consume: register-only asm (invisible to the waitcnt pass), reads the
    // ring slot (16B/lane, conflict-free) + the scale, waits lgkm inside.
    f4 cx0, cx1;
    float scale;
    auto consume = [&](int tc, f4& o0, f4& o1, float& os) {
        lds_cfp rx = (lds_cfp)(const float*)ring + (size_t)(tc & 7) * 512 + 4 * l;
        int ts = (tc > T_SEQ - 1) ? (T_SEQ - 1) : tc;
        lds_cfp sp = (lds_cfp)(const float*)slds + ts * 16 + m;
        f4 a, b; float sv;
        asm volatile("ds_read_b128 %0, %3\n\t"
                     "ds_read_b128 %1, %3 offset:1024\n\t"
                     "ds_read_b32 %2, %4\n\t"
                     "s_waitcnt lgkmcnt(0)"
                     : "=&v"(a), "=&v"(b), "=&v"(sv)
                     : "v"(rx), "v"(sp));
        float xt[8] = { a[0], a[1], a[2], a[3], b[0], b[1], b[2], b[3] };
        bfrag xf; pack8(xt, xf);
        o0 = mfma_(X0, xf, cb0);
        o1 = mfma_(X1, xf, cb1);
        os = sv;
    };

    asm volatile("s_waitcnt vmcnt(12)");
    consume(0, cx0, cx1, scale);

    #pragma unroll 1
    for (int t = 0; t < T_SEQ; ++t) {
        // prefetch time t+7 (clamped content, constant op count, rotating slot)
        int tf = t + 7; if (tf > T_SEQ - 1) tf = T_SEQ - 1;
        issue2(tf, (t + 7) & 7);

        asm volatile("s_waitcnt vmcnt(12)");

        f4 ncx0, ncx1; float nsc;
        consume(t + 1, ncx0, ncx1, nsc);   // data landed several bodies ago

        // ---- Euler body for time t ----
        const float s2 = scale + scale;
        bfrag bb; pack8(z, bb);
        f4 p0 = mfma_(A0, bb, cx0);
        f4 p1 = mfma_(A1, bb, cx1);
        float pr[8];
        #pragma unroll
        for (int r = 0; r < 4; ++r) {
            pr[r]     = fmaxf(p0[r], 0.0f);
            pr[4 + r] = fmaxf(p1[r], 0.0f);
        }
        bfrag pf; pack8(pr, pf);
        f4 o0 = mfma_(W0, pf, bias0);
        f4 o1 = mfma_(W1, pf, bias1);
        #pragma unroll
        for (int r = 0; r < 4; ++r) {
            z[r]     += tanh_mul(o0[r], scale, s2);
            z[4 + r] += tanh_mul(o1[r], scale, s2);
        }
        bfrag zf; pack8(z, zf);
        FragU P; P.v = zf;
        uint32_t* rowp = zrow + (uint32_t)t * 16;
        *(uint2*)(rowp + 2 * g)     = make_uint2(P.u[0], P.u[1]);
        *(uint2*)(rowp + 8 + 2 * g) = make_uint2(P.u[2], P.u[3]);

        cx0 = ncx0; cx1 = ncx1; scale = nsc;
    }
}

// Parallel mu head: one thread per (e,t) row.
__global__ __launch_bounds__(256, 4)
void mu_kernel(const uint32_t* __restrict__ zws,
               const float* __restrict__ Wm1, const float* __restrict__ bm1,
               const float* __restrict__ Wm2, const float* __restrict__ bm2,
               float* __restrict__ out, int nrows)
{
    int row = blockIdx.x * 256 + threadIdx.x;
    if (row >= nrows) return;
    const uint4* zp = (const uint4*)(zws + (size_t)row * 16);
    uint4 q0 = zp[0], q1 = zp[1], q2 = zp[2], q3 = zp[3];
    uint32_t du[16] = { q0.x, q0.y, q0.z, q0.w, q1.x, q1.y, q1.z, q1.w,
                        q2.x, q2.y, q2.z, q2.w, q3.x, q3.y, q3.z, q3.w };
    float zf[32];
    #pragma unroll
    for (int d = 0; d < 16; ++d) {
        uint32_t u = du[d];
        zf[2 * d]     = __uint_as_float(u << 16);
        zf[2 * d + 1] = __uint_as_float(u & 0xFFFF0000u);
    }
    float v[10];
    #pragma unroll
    for (int r = 0; r < 10; ++r) v[r] = bm1[r];
    #pragma unroll
    for (int i = 0; i < 32; ++i) {
        float zi = zf[i];
        #pragma unroll
        for (int r = 0; r < 10; ++r) v[r] = fmaf(zi, Wm1[i * 10 + r], v[r]);
    }
    float mu = bm2[0];
    #pragma unroll
    for (int r = 0; r < 10; ++r) mu += fast_tanh(v[r]) * Wm2[r];
    out[row] = mu;
}

// ============================================================================
// Fallback (ws too small / B not /16): fused Euler, mu in-loop.
// ============================================================================
__global__ __launch_bounds__(64, 1)
void latode_fused(const float* __restrict__ dt,  const float* __restrict__ x,
                  const float* __restrict__ We1, const float* __restrict__ be1,
                  const float* __restrict__ We2, const float* __restrict__ be2,
                  const float* __restrict__ Wf1, const float* __restrict__ bf1,
                  const float* __restrict__ Wf2, const float* __restrict__ bf2,
                  const float* __restrict__ Wm1, const float* __restrict__ bm1,
                  const float* __restrict__ Wm2, const float* __restrict__ bm2,
                  float* __restrict__ out, int B)
{
    const int l = threadIdx.x;
    const int g = l >> 4;
    const int m = l & 15;
    const int e = blockIdx.x * 16 + m;
    if (e >= B) return;
    const int js0 = 8 * (m >> 2) + (m & 3);
    const int js1 = js0 + 4;

    float tmp[8];
    bfrag A0, A1, X0, X1, W0, W1, M0;
    #pragma unroll
    for (int jj = 0; jj < 8; ++jj) {
        int sig = 16 * (jj >> 2) + 4 * g + (jj & 3);
        tmp[jj] = (js0 < 20) ? Wf1[sig * 20 + js0] : 0.0f;
    }
    pack8(tmp, A0);
    #pragma unroll
    for (int jj = 0; jj < 8; ++jj) {
        int sig = 16 * (jj >> 2) + 4 * g + (jj & 3);
        tmp[jj] = (js1 < 20) ? Wf1[sig * 20 + js1] : 0.0f;
    }
    pack8(tmp, A1);
    #pragma unroll
    for (int jj = 0; jj < 8; ++jj) {
        int kx = 8 * g + jj;
        tmp[jj] = (js0 < 20) ? Wf1[(32 + kx) * 20 + js0] : 0.0f;
    }
    pack8(tmp, X0);
    #pragma unroll
    for (int jj = 0; jj < 8; ++jj) {
        int kx = 8 * g + jj;
        tmp[jj] = (js1 < 20) ? Wf1[(32 + kx) * 20 + js1] : 0.0f;
    }
    pack8(tmp, X1);
    #pragma unroll
    for (int jj = 0; jj < 8; ++jj) {
        int j = 8 * g + jj;
        tmp[jj] = (j < 20) ? Wf2[j * 32 + m] : 0.0f;
    }
    pack8(tmp, W0);
    #pragma unroll
    for (int jj = 0; jj < 8; ++jj) {
        int j = 8 * g + jj;
        tmp[jj] = (j < 20) ? Wf2[j * 32 + 16 + m] : 0.0f;
    }
    pack8(tmp, W1);
    #pragma unroll
    for (int jj = 0; jj < 8; ++jj) {
        int sig = 16 * (jj >> 2) + 4 * g + (jj & 3);
        tmp[jj] = (m < 10) ? Wm1[sig * 10 + m] : 0.0f;
    }
    pack8(tmp, M0);

    f4 bias0, bias1, cb0, cb1, bmv;
    float wm2r[4];
    #pragma unroll
    for (int r = 0; r < 4; ++r) {
        bias0[r] = bf2[4 * g + r];
        bias1[r] = bf2[16 + 4 * g + r];
        int j0 = 8 * g + r;     cb0[r] = (j0 < 20) ? bf1[j0] : 0.0f;
        int j1 = 8 * g + r + 4; cb1[r] = (j1 < 20) ? bf1[j1] : 0.0f;
        int vr = 4 * g + r;
        bmv[r]  = (vr < 10) ? bm1[vr] : 0.0f;
        wm2r[r] = (vr < 10) ? Wm2[vr] : 0.0f;
    }

    const float* xe  = x  + (size_t)e * T_SEQ * 32;
    const float* dte = dt + (size_t)e * T_SEQ * 2;

    float z[8];
    {
        float x0v[32];
        #pragma unroll
        for (int i = 0; i < 32; i += 4) {
            float4 v = *(const float4*)(xe + i);
            x0v[i] = v.x; x0v[i+1] = v.y; x0v[i+2] = v.z; x0v[i+3] = v.w;
        }
        float h10[10];
        #pragma unroll
        for (int r = 0; r < 10; ++r) {
            float s = be1[r];
            #pragma unroll
            for (int i = 0; i < 32; ++i) s += x0v[i] * We1[i * 10 + r];
            h10[r] = fast_tanh(s);
        }
        #pragma unroll
        for (int jj = 0; jj < 8; ++jj) {
            int sig = 16 * (jj >> 2) + 4 * g + (jj & 3);
            float s = be2[sig];
            #pragma unroll
            for (int r = 0; r < 10; ++r) s += h10[r] * We2[r * 32 + sig];
            z[jj] = fast_tanh(s);
        }
    }

    const float bm2s = bm2[0];
    f4 cx0, cx1;
    float scale;
    {
        float4 va = *(const float4*)(xe + 8 * g);
        float4 vb = *(const float4*)(xe + 8 * g + 4);
        float2 dd = *(const float2*)(dte);
        float xt[8] = { va.x, va.y, va.z, va.w, vb.x, vb.y, vb.z, vb.w };
        bfrag xf; pack8(xt, xf);
        cx0 = mfma_(X0, xf, cb0);
        cx1 = mfma_(X1, xf, cb1);
        scale = (dd.y - dd.x) * 0.01f;
    }

    for (int t = 0; t < T_SEQ; ++t) {
        int tn = (t + 1 < T_SEQ) ? (t + 1) : t;
        const float* xr = xe + tn * 32 + 8 * g;
        float4 na = *(const float4*)(xr);
        float4 nb = *(const float4*)(xr + 4);
        float2 nd = *(const float2*)(dte + 2 * tn);
        const float s2 = scale + scale;

        bfrag bb; pack8(z, bb);
        f4 p0 = mfma_(A0, bb, cx0);
        f4 p1 = mfma_(A1, bb, cx1);
        float pr[8];
        #pragma unroll
        for (int r = 0; r < 4; ++r) {
            pr[r]     = fmaxf(p0[r], 0.0f);
            pr[4 + r] = fmaxf(p1[r], 0.0f);
        }
        bfrag pf; pack8(pr, pf);
        f4 o0 = mfma_(W0, pf, bias0);
        f4 o1 = mfma_(W1, pf, bias1);
        #pragma unroll
        for (int r = 0; r < 4; ++r) {
            z[r]     += tanh_mul(o0[r], scale, s2);
            z[4 + r] += tanh_mul(o1[r], scale, s2);
        }

        {
            float xt[8] = { na.x, na.y, na.z, na.w, nb.x, nb.y, nb.z, nb.w };
            bfrag xf; pack8(xt, xf);
            cx0 = mfma_(X0, xf, cb0);
            cx1 = mfma_(X1, xf, cb1);
            scale = (nd.y - nd.x) * 0.01f;
        }

        bfrag zf; pack8(z, zf);
        f4 vv = mfma_(M0, zf, bmv);
        float p = 0.0f;
        #pragma unroll
        for (int r = 0; r < 4; ++r) p += fast_tanh(vv[r]) * wm2r[r];
        p += __shfl_xor(p, 16, 64);
        p += __shfl_xor(p, 32, 64);
        if (l < 16) out[(size_t)e * T_SEQ + t] = p + bm2s;
    }
}

extern "C" void kernel_launch(void* const* d_in, const int* in_sizes, int n_in,
                              void* d_out, int out_size, void* d_ws, size_t ws_size,
                              hipStream_t stream) {
    const float* dt  = (const float*)d_in[0];
    const float* x   = (const float*)d_in[1];
    const float* We1 = (const float*)d_in[2];
    const float* be1 = (const float*)d_in[3];
    const float* We2 = (const float*)d_in[4];
    const float* be2 = (const float*)d_in[5];
    const float* Wf1 = (const float*)d_in[6];
    const float* bf1 = (const float*)d_in[7];
    const float* Wf2 = (const float*)d_in[8];
    const float* bf2 = (const float*)d_in[9];
    const float* Wm1 = (const float*)d_in[10];
    const float* bm1 = (const float*)d_in[11];
    const float* Wm2 = (const float*)d_in[12];
    const float* bm2 = (const float*)d_in[13];
    float* out = (float*)d_out;

    const int B = in_sizes[0] / (T_SEQ * 2);   // 8192
    const size_t zbytes = (size_t)B * T_SEQ * 32 * 2;

    if (ws_size >= zbytes && (B % 16) == 0) {
        hipLaunchKernelGGL(latode_serial, dim3(B / 16), dim3(64), 0, stream,
                           dt, x, We1, be1, We2, be2, Wf1, bf1, Wf2, bf2,
                           (uint32_t*)d_ws, B);
        int nrows = B * T_SEQ;
        hipLaunchKernelGGL(mu_kernel, dim3((nrows + 255) / 256), dim3(256), 0, stream,
                           (const uint32_t*)d_ws, Wm1, bm1, Wm2, bm2, out, nrows);
    } else {
        hipLaunchKernelGGL(latode_fused, dim3((B + 15) / 16), dim3(64), 0, stream,
                           dt, x, We1, be1, We2, be2, Wf1, bf1, Wf2, bf2,
                           Wm1, bm1, Wm2, bm2, out, B);
    }
}

// Round 8
// 205.295 us; speedup vs baseline: 1.3452x; 1.0874x over previous
//
#include <hip/hip_runtime.h>
#include <cstddef>
#include <cstdint>

#define T_SEQ 100

typedef __attribute__((ext_vector_type(8))) short bfrag;
typedef __attribute__((ext_vector_type(4))) float f4;

union FragU { uint32_t u[4]; bfrag v; };

__device__ __forceinline__ float fast_tanh(float x) {
    float e = __expf(2.0f * x);
    float r = __builtin_amdgcn_rcpf(e + 1.0f);
    return 1.0f - 2.0f * r;
}

__device__ __forceinline__ float exp2_fast(float x) {
#if __has_builtin(__builtin_amdgcn_exp2f)
    return __builtin_amdgcn_exp2f(x);
#else
    return __expf(x * 0.6931471805599453f);
#endif
}

// tanh(o)*scale = scale - 2*scale / (2^(o*2*log2e) + 1)
__device__ __forceinline__ float tanh_mul(float o, float scale, float s2) {
    float rr = __builtin_amdgcn_rcpf(exp2_fast(o * 2.8853900817779268f) + 1.0f);
    return fmaf(-s2, rr, scale);
}

// f32 pair -> packed bf16 (RNE), one instruction per pair (register-only asm).
#if __has_builtin(__builtin_amdgcn_cvt_pk_bf16_f32)
typedef __attribute__((ext_vector_type(2))) __bf16 bf16x2;
__device__ __forceinline__ uint32_t cvtpk(float lo, float hi) {
    bf16x2 p = __builtin_amdgcn_cvt_pk_bf16_f32(lo, hi);
    return __builtin_bit_cast(uint32_t, p);
}
#else
__device__ __forceinline__ uint32_t cvtpk(float lo, float hi) {
    uint32_t r;
    asm("v_cvt_pk_bf16_f32 %0, %1, %2" : "=v"(r) : "v"(lo), "v"(hi));
    return r;
}
#endif

__device__ __forceinline__ void pack8(const float a[8], bfrag& out) {
    FragU O;
    #pragma unroll
    for (int q = 0; q < 4; ++q)
        O.u[q] = cvtpk(a[2 * q], a[2 * q + 1]);
    out = O.v;
}

__device__ __forceinline__ f4 mfma_(bfrag a, bfrag b, f4 c) {
    return __builtin_amdgcn_mfma_f32_16x16x32_bf16(a, b, c, 0, 0, 0);
}

// 16B global->LDS async copy, verified configuration (size=16, offset=0,
// true addrspacecast pointers). Lane lambda's 16B land at lds_base+lambda*16.
__device__ __forceinline__ void gl_lds16(const float* gp, float* lp) {
#if __has_builtin(__builtin_amdgcn_global_load_lds)
    __builtin_amdgcn_global_load_lds(
        (const __attribute__((address_space(1))) void*)gp,
        (__attribute__((address_space(3))) void*)lp,
        16, 0, 0);
#else
    #pragma unroll
    for (int j = 0; j < 4; ++j) lp[4 * threadIdx.x + j] = gp[j];
#endif
}

typedef __attribute__((address_space(3))) const float* lds_cfp;

// ============================================================================
// FUSED serial recurrence + mu: one wave = 16 elements, Euler (1 feval/t).
// r5-validated ring (global_load_lds, counted vmcnt, asm ds_read) with two
// changes:
//  (1) split consume: dsissue(t+2) issues the 3 ds_reads one body early;
//      finish() does s_waitcnt lgkmcnt(0) + sched_barrier(0) (rule-18 fence)
//      then pack+cx-MFMAs — the ~120-300cy LDS latency overlaps the previous
//      body's feval instead of sitting on the serial chain.
//  (2) mu computed in-loop with the VALIDATED latode_fused pattern
//      (M0 mfma + shfl_xor(16,32) + masked scalar store) — deletes the
//      per-body z-stores, the 52MB zws write/read, and the mu_kernel launch.
// vmcnt counts (in-order retire): at each body >=10 loads are newer than
// L(t+2), so vmcnt(10) guarantees the slot read by dsissue(t+2); extra vmem
// ops (stores/spills) only ADD newer ops -> scheme is spill-robust.
// Prologue: vmcnt(12) for L(0) (12 newer loads), vmcnt(10) for L(1).
// ============================================================================
__global__ __launch_bounds__(64, 1)
void latode_serial(const float* __restrict__ dt,  const float* __restrict__ x,
                   const float* __restrict__ We1, const float* __restrict__ be1,
                   const float* __restrict__ We2, const float* __restrict__ be2,
                   const float* __restrict__ Wf1, const float* __restrict__ bf1,
                   const float* __restrict__ Wf2, const float* __restrict__ bf2,
                   const float* __restrict__ Wm1, const float* __restrict__ bm1,
                   const float* __restrict__ Wm2, const float* __restrict__ bm2,
                   float* __restrict__ out, int B)
{
    const int l = threadIdx.x;
    const int g = l >> 4;
    const int m = l & 15;
    const int e = blockIdx.x * 16 + m;
    const int js0 = 8 * (m >> 2) + (m & 3);
    const int js1 = js0 + 4;

    __shared__ __align__(16) float slds[T_SEQ * 16];  // scale[t][e_local]
    __shared__ __align__(16) float ring[8 * 512];     // 8 slots x 2048 B

    float tmp[8];
    bfrag A0, A1, X0, X1, W0, W1, M0;

    #pragma unroll
    for (int jj = 0; jj < 8; ++jj) {
        int sig = 16 * (jj >> 2) + 4 * g + (jj & 3);
        tmp[jj] = (js0 < 20) ? Wf1[sig * 20 + js0] : 0.0f;
    }
    pack8(tmp, A0);
    #pragma unroll
    for (int jj = 0; jj < 8; ++jj) {
        int sig = 16 * (jj >> 2) + 4 * g + (jj & 3);
        tmp[jj] = (js1 < 20) ? Wf1[sig * 20 + js1] : 0.0f;
    }
    pack8(tmp, A1);
    #pragma unroll
    for (int jj = 0; jj < 8; ++jj) {
        int kx = 8 * g + jj;
        tmp[jj] = (js0 < 20) ? Wf1[(32 + kx) * 20 + js0] : 0.0f;
    }
    pack8(tmp, X0);
    #pragma unroll
    for (int jj = 0; jj < 8; ++jj) {
        int kx = 8 * g + jj;
        tmp[jj] = (js1 < 20) ? Wf1[(32 + kx) * 20 + js1] : 0.0f;
    }
    pack8(tmp, X1);
    #pragma unroll
    for (int jj = 0; jj < 8; ++jj) {
        int j = 8 * g + jj;
        tmp[jj] = (j < 20) ? Wf2[j * 32 + m] : 0.0f;
    }
    pack8(tmp, W0);
    #pragma unroll
    for (int jj = 0; jj < 8; ++jj) {
        int j = 8 * g + jj;
        tmp[jj] = (j < 20) ? Wf2[j * 32 + 16 + m] : 0.0f;
    }
    pack8(tmp, W1);
    // mu frag — VERBATIM from the validated latode_fused kernel
    #pragma unroll
    for (int jj = 0; jj < 8; ++jj) {
        int sig = 16 * (jj >> 2) + 4 * g + (jj & 3);
        tmp[jj] = (m < 10) ? Wm1[sig * 10 + m] : 0.0f;
    }
    pack8(tmp, M0);

    f4 bias0, bias1, cb0, cb1, bmv;
    float wm2r[4];
    #pragma unroll
    for (int r = 0; r < 4; ++r) {
        bias0[r] = bf2[4 * g + r];
        bias1[r] = bf2[16 + 4 * g + r];
        int j0 = 8 * g + r;     cb0[r] = (j0 < 20) ? bf1[j0] : 0.0f;
        int j1 = 8 * g + r + 4; cb1[r] = (j1 < 20) ? bf1[j1] : 0.0f;
        int vr = 4 * g + r;
        bmv[r]  = (vr < 10) ? bm1[vr] : 0.0f;
        wm2r[r] = (vr < 10) ? Wm2[vr] : 0.0f;
    }
    const float bm2s = bm2[0];

    const float* xe = x + (size_t)e * T_SEQ * 32;

    // ---- stage scales into LDS (one-time, plain ops, before any DMA) ----
    {
        const float* dtb = dt + (size_t)blockIdx.x * 16 * T_SEQ * 2;  // 3200 f
        #pragma unroll 1
        for (int i = l; i < 800; i += 64) {
            float4 v = *(const float4*)(dtb + 4 * i);
            int p0 = 2 * i;            // even pair index
            int el = p0 / 100;         // element 0..15
            int t0 = p0 - el * 100;    // even, <= 98
            slds[t0 * 16 + el]       = (v.y - v.x) * 0.01f;
            slds[(t0 + 1) * 16 + el] = (v.w - v.z) * 0.01f;
        }
    }

    // ---- z0 encode (scalar fp32, once; before the ring prefill) ----
    float z[8];
    {
        float x0v[32];
        #pragma unroll
        for (int i = 0; i < 32; i += 4) {
            float4 v = *(const float4*)(xe + i);
            x0v[i] = v.x; x0v[i+1] = v.y; x0v[i+2] = v.z; x0v[i+3] = v.w;
        }
        float h10[10];
        #pragma unroll
        for (int r = 0; r < 10; ++r) {
            float s = be1[r];
            #pragma unroll
            for (int i = 0; i < 32; ++i) s += x0v[i] * We1[i * 10 + r];
            h10[r] = fast_tanh(s);
        }
        #pragma unroll
        for (int jj = 0; jj < 8; ++jj) {
            int sig = 16 * (jj >> 2) + 4 * g + (jj & 3);
            float s = be2[sig];
            #pragma unroll
            for (int r = 0; r < 10; ++r) s += h10[r] * We2[r * 32 + sig];
            z[jj] = fast_tanh(s);
        }
    }
    bfrag zb; pack8(z, zb);            // packed z, maintained across bodies

    // ---- ring prefill: times 0..6 into slots 0..6 (14 loads in flight) ----
    const float* xg = xe + 8 * g;
    auto issue2 = [&](int tf, int slot) {
        const float* gp = xg + (size_t)tf * 32;
        float* lp = ring + slot * 512;
        gl_lds16(gp,     lp);
        gl_lds16(gp + 4, lp + 256);
    };
    #pragma unroll
    for (int tau = 0; tau < 7; ++tau) issue2(tau, tau);

    // dsissue: issue the 3 ds_reads for slot tc (no wait — latency overlaps
    // the current body). finish: counted lgkm wait + rule-18 fence, then use.
    auto dsissue = [&](int tc, f4& a, f4& b, float& sv) {
        lds_cfp rx = (lds_cfp)(const float*)ring + (size_t)(tc & 7) * 512 + 4 * l;
        int ts = (tc > T_SEQ - 1) ? (T_SEQ - 1) : tc;
        lds_cfp sp = (lds_cfp)(const float*)slds + ts * 16 + m;
        asm volatile("ds_read_b128 %0, %3\n\t"
                     "ds_read_b128 %1, %3 offset:1024\n\t"
                     "ds_read_b32 %2, %4"
                     : "=&v"(a), "=&v"(b), "=&v"(sv)
                     : "v"(rx), "v"(sp));
    };
    auto finish = [&](f4& o0, f4& o1, float& os,
                      const f4& a, const f4& b, float sv) {
        asm volatile("s_waitcnt lgkmcnt(0)");
        __builtin_amdgcn_sched_barrier(0);
        float xt[8] = { a[0], a[1], a[2], a[3], b[0], b[1], b[2], b[3] };
        bfrag xf; pack8(xt, xf);
        o0 = mfma_(X0, xf, cb0);
        o1 = mfma_(X1, xf, cb1);
        os = sv;
    };

    // ---- prologue of the split pipeline ----
    f4 pa, pb; float ps;
    f4 cx0, cx1; float scale;
    asm volatile("s_waitcnt vmcnt(12)");   // L(0) landed (12 newer loads)
    dsissue(0, pa, pb, ps);
    asm volatile("s_waitcnt vmcnt(10)");   // L(1) landed (10 newer loads)
    finish(cx0, cx1, scale, pa, pb, ps);   // cx for t=0
    dsissue(1, pa, pb, ps);                // pending reads for t=1

    #pragma unroll 1
    for (int t = 0; t < T_SEQ; ++t) {
        int tf = t + 7; if (tf > T_SEQ - 1) tf = T_SEQ - 1;
        issue2(tf, (t + 7) & 7);

        asm volatile("s_waitcnt vmcnt(10)");   // L(t+2) landed

        f4 ncx0, ncx1; float nsc;
        finish(ncx0, ncx1, nsc, pa, pb, ps);   // slot t+1 (issued last body)
        dsissue(t + 2, pa, pb, ps);            // overlaps this body's feval

        // ---- Euler body for time t ----
        const float s2 = scale + scale;
        f4 p0 = mfma_(A0, zb, cx0);
        f4 p1 = mfma_(A1, zb, cx1);
        float pr[8];
        #pragma unroll
        for (int r = 0; r < 4; ++r) {
            pr[r]     = fmaxf(p0[r], 0.0f);
            pr[4 + r] = fmaxf(p1[r], 0.0f);
        }
        bfrag pf; pack8(pr, pf);
        f4 o0 = mfma_(W0, pf, bias0);
        f4 o1 = mfma_(W1, pf, bias1);
        #pragma unroll
        for (int r = 0; r < 4; ++r) {
            z[r]     += tanh_mul(o0[r], scale, s2);
            z[4 + r] += tanh_mul(o1[r], scale, s2);
        }
        pack8(z, zb);                          // z(t+1) packed (feeds next body)

        // ---- mu head: VERBATIM validated latode_fused pattern ----
        f4 vv = mfma_(M0, zb, bmv);
        float p = 0.0f;
        #pragma unroll
        for (int r = 0; r < 4; ++r) p += fast_tanh(vv[r]) * wm2r[r];
        p += __shfl_xor(p, 16, 64);
        p += __shfl_xor(p, 32, 64);
        if (l < 16) out[(size_t)e * T_SEQ + t] = p + bm2s;

        cx0 = ncx0; cx1 = ncx1; scale = nsc;
    }
}

// ============================================================================
// Fallback (B not /16): fused Euler, mu in-loop (unchanged, validated).
// ============================================================================
__global__ __launch_bounds__(64, 1)
void latode_fused(const float* __restrict__ dt,  const float* __restrict__ x,
                  const float* __restrict__ We1, const float* __restrict__ be1,
                  const float* __restrict__ We2, const float* __restrict__ be2,
                  const float* __restrict__ Wf1, const float* __restrict__ bf1,
                  const float* __restrict__ Wf2, const float* __restrict__ bf2,
                  const float* __restrict__ Wm1, const float* __restrict__ bm1,
                  const float* __restrict__ Wm2, const float* __restrict__ bm2,
                  float* __restrict__ out, int B)
{
    const int l = threadIdx.x;
    const int g = l >> 4;
    const int m = l & 15;
    const int e = blockIdx.x * 16 + m;
    if (e >= B) return;
    const int js0 = 8 * (m >> 2) + (m & 3);
    const int js1 = js0 + 4;

    float tmp[8];
    bfrag A0, A1, X0, X1, W0, W1, M0;
    #pragma unroll
    for (int jj = 0; jj < 8; ++jj) {
        int sig = 16 * (jj >> 2) + 4 * g + (jj & 3);
        tmp[jj] = (js0 < 20) ? Wf1[sig * 20 + js0] : 0.0f;
    }
    pack8(tmp, A0);
    #pragma unroll
    for (int jj = 0; jj < 8; ++jj) {
        int sig = 16 * (jj >> 2) + 4 * g + (jj & 3);
        tmp[jj] = (js1 < 20) ? Wf1[sig * 20 + js1] : 0.0f;
    }
    pack8(tmp, A1);
    #pragma unroll
    for (int jj = 0; jj < 8; ++jj) {
        int kx = 8 * g + jj;
        tmp[jj] = (js0 < 20) ? Wf1[(32 + kx) * 20 + js0] : 0.0f;
    }
    pack8(tmp, X0);
    #pragma unroll
    for (int jj = 0; jj < 8; ++jj) {
        int kx = 8 * g + jj;
        tmp[jj] = (js1 < 20) ? Wf1[(32 + kx) * 20 + js1] : 0.0f;
    }
    pack8(tmp, X1);
    #pragma unroll
    for (int jj = 0; jj < 8; ++jj) {
        int j = 8 * g + jj;
        tmp[jj] = (j < 20) ? Wf2[j * 32 + m] : 0.0f;
    }
    pack8(tmp, W0);
    #pragma unroll
    for (int jj = 0; jj < 8; ++jj) {
        int j = 8 * g + jj;
        tmp[jj] = (j < 20) ? Wf2[j * 32 + 16 + m] : 0.0f;
    }
    pack8(tmp, W1);
    #pragma unroll
    for (int jj = 0; jj < 8; ++jj) {
        int sig = 16 * (jj >> 2) + 4 * g + (jj & 3);
        tmp[jj] = (m < 10) ? Wm1[sig * 10 + m] : 0.0f;
    }
    pack8(tmp, M0);

    f4 bias0, bias1, cb0, cb1, bmv;
    float wm2r[4];
    #pragma unroll
    for (int r = 0; r < 4; ++r) {
        bias0[r] = bf2[4 * g + r];
        bias1[r] = bf2[16 + 4 * g + r];
        int j0 = 8 * g + r;     cb0[r] = (j0 < 20) ? bf1[j0] : 0.0f;
        int j1 = 8 * g + r + 4; cb1[r] = (j1 < 20) ? bf1[j1] : 0.0f;
        int vr = 4 * g + r;
        bmv[r]  = (vr < 10) ? bm1[vr] : 0.0f;
        wm2r[r] = (vr < 10) ? Wm2[vr] : 0.0f;
    }

    const float* xe  = x  + (size_t)e * T_SEQ * 32;
    const float* dte = dt + (size_t)e * T_SEQ * 2;

    float z[8];
    {
        float x0v[32];
        #pragma unroll
        for (int i = 0; i < 32; i += 4) {
            float4 v = *(const float4*)(xe + i);
            x0v[i] = v.x; x0v[i+1] = v.y; x0v[i+2] = v.z; x0v[i+3] = v.w;
        }
        float h10[10];
        #pragma unroll
        for (int r = 0; r < 10; ++r) {
            float s = be1[r];
            #pragma unroll
            for (int i = 0; i < 32; ++i) s += x0v[i] * We1[i * 10 + r];
            h10[r] = fast_tanh(s);
        }
        #pragma unroll
        for (int jj = 0; jj < 8; ++jj) {
            int sig = 16 * (jj >> 2) + 4 * g + (jj & 3);
            float s = be2[sig];
            #pragma unroll
            for (int r = 0; r < 10; ++r) s += h10[r] * We2[r * 32 + sig];
            z[jj] = fast_tanh(s);
        }
    }

    const float bm2s = bm2[0];
    f4 cx0, cx1;
    float scale;
    {
        float4 va = *(const float4*)(xe + 8 * g);
        float4 vb = *(const float4*)(xe + 8 * g + 4);
        float2 dd = *(const float2*)(dte);
        float xt[8] = { va.x, va.y, va.z, va.w, vb.x, vb.y, vb.z, vb.w };
        bfrag xf; pack8(xt, xf);
        cx0 = mfma_(X0, xf, cb0);
        cx1 = mfma_(X1, xf, cb1);
        scale = (dd.y - dd.x) * 0.01f;
    }

    for (int t = 0; t < T_SEQ; ++t) {
        int tn = (t + 1 < T_SEQ) ? (t + 1) : t;
        const float* xr = xe + tn * 32 + 8 * g;
        float4 na = *(const float4*)(xr);
        float4 nb = *(const float4*)(xr + 4);
        float2 nd = *(const float2*)(dte + 2 * tn);
        const float s2 = scale + scale;

        bfrag bb; pack8(z, bb);
        f4 p0 = mfma_(A0, bb, cx0);
        f4 p1 = mfma_(A1, bb, cx1);
        float pr[8];
        #pragma unroll
        for (int r = 0; r < 4; ++r) {
            pr[r]     = fmaxf(p0[r], 0.0f);
            pr[4 + r] = fmaxf(p1[r], 0.0f);
        }
        bfrag pf; pack8(pr, pf);
        f4 o0 = mfma_(W0, pf, bias0);
        f4 o1 = mfma_(W1, pf, bias1);
        #pragma unroll
        for (int r = 0; r < 4; ++r) {
            z[r]     += tanh_mul(o0[r], scale, s2);
            z[4 + r] += tanh_mul(o1[r], scale, s2);
        }

        {
            float xt[8] = { na.x, na.y, na.z, na.w, nb.x, nb.y, nb.z, nb.w };
            bfrag xf; pack8(xt, xf);
            cx0 = mfma_(X0, xf, cb0);
            cx1 = mfma_(X1, xf, cb1);
            scale = (nd.y - nd.x) * 0.01f;
        }

        bfrag zf; pack8(z, zf);
        f4 vv = mfma_(M0, zf, bmv);
        float p = 0.0f;
        #pragma unroll
        for (int r = 0; r < 4; ++r) p += fast_tanh(vv[r]) * wm2r[r];
        p += __shfl_xor(p, 16, 64);
        p += __shfl_xor(p, 32, 64);
        if (l < 16) out[(size_t)e * T_SEQ + t] = p + bm2s;
    }
}

extern "C" void kernel_launch(void* const* d_in, const int* in_sizes, int n_in,
                              void* d_out, int out_size, void* d_ws, size_t ws_size,
                              hipStream_t stream) {
    const float* dt  = (const float*)d_in[0];
    const float* x   = (const float*)d_in[1];
    const float* We1 = (const float*)d_in[2];
    const float* be1 = (const float*)d_in[3];
    const float* We2 = (const float*)d_in[4];
    const float* be2 = (const float*)d_in[5];
    const float* Wf1 = (const float*)d_in[6];
    const float* bf1 = (const float*)d_in[7];
    const float* Wf2 = (const float*)d_in[8];
    const float* bf2 = (const float*)d_in[9];
    const float* Wm1 = (const float*)d_in[10];
    const float* bm1 = (const float*)d_in[11];
    const float* Wm2 = (const float*)d_in[12];
    const float* bm2 = (const float*)d_in[13];
    float* out = (float*)d_out;

    const int B = in_sizes[0] / (T_SEQ * 2);   // 8192

    if ((B % 16) == 0) {
        hipLaunchKernelGGL(latode_serial, dim3(B / 16), dim3(64), 0, stream,
                           dt, x, We1, be1, We2, be2, Wf1, bf1, Wf2, bf2,
                           Wm1, bm1, Wm2, bm2, out, B);
    } else {
        hipLaunchKernelGGL(latode_fused, dim3((B + 15) / 16), dim3(64), 0, stream,
                           dt, x, We1, be1, We2, be2, Wf1, bf1, Wf2, bf2,
                           Wm1, bm1, Wm2, bm2, out, B);
    }
}